// Round 8
// baseline (365.307 us; speedup 1.0000x reference)
//
#include <hip/hip_runtime.h>

#define NT 1024
#define RPT 8
#define NITER 200

typedef float v2f __attribute__((ext_vector_type(2)));

// v += dpp-partner(v).  CTRL: 0x128=row_ror:8 (==xor8 in 16-row),
// 0xB1=quad_perm(1,0,3,2)==xor1, 0x4E=quad_perm(2,3,0,1)==xor2,
// 0x141=row_half_mirror (==xor4 once xor1,xor2 are done).
template <int CTRL>
__device__ __forceinline__ float dpp_add(float v) {
  int x = __builtin_amdgcn_update_dpp(0, __float_as_int(v), CTRL, 0xF, 0xF, true);
  return v + __int_as_float(x);
}

__device__ __forceinline__ float wsum(float v) {
  v += __shfl_xor(v, 1);
  v += __shfl_xor(v, 2);
  v += __shfl_xor(v, 4);
  v += __shfl_xor(v, 8);
  v += __shfl_xor(v, 16);
  v += __shfl_xor(v, 32);
  return v;
}

// Sinkhorn, scale-invariant multiplicative form with STATIC e between
// refreshes. Round-7 passing kernel with ONE delta: uniform early exit
// when the fixed point is reached (max_j |R_j - 1| < 3e-6 for t > 24).
// Rationale: rounds 1/2/5/6/7 give bit-identical absmax despite different
// rounding -> the map contracts to the fixed point well before t=200, so
// tail iterations are numerically idle. R2 is block-uniform (LDS
// broadcast), so the branch is uniform: all waves exit at the same t and
// the epilogue sees the same (w0k, R2) relationship as the natural end.
__global__ void __launch_bounds__(NT)
__attribute__((amdgpu_waves_per_eu(4, 4)))
sinkhorn_k(
    const float* __restrict__ theta,
    const float* __restrict__ phi,
    const float* __restrict__ sens_raw,
    const float* __restrict__ n_raw,
    float* __restrict__ out)
{
  constexpr float S1C = 72.13475204444817f;      // (1/EPS) * log2(e)
  constexpr float L2E = 1.4426950408889634f;
  constexpr float CLAMP = 1.152921504606847e18f; // 2^60
  constexpr float ERR0 = 6.25e-2f;               // 2^-4   (bits=2)
  constexpr float ERR1 = 1.5625e-2f;             // 2^-6   (bits=3)
  constexpr float ERR2 = 3.90625e-3f;            // 2^-8   (bits=4)
  constexpr float ERR3 = 9.765625e-4f;           // 2^-10  (bits=5)
  constexpr float ERR4 = 2.44140625e-4f;         // 2^-12  (bits=6)
  constexpr float ERR5 = 1.52587890625e-5f;      // 2^-16  (bits=8)
  constexpr float ERR6 = 9.5367431640625e-7f;    // 2^-20  (bits=10)
  constexpr float ERR7 = 5.9604644775390625e-8f; // 2^-24  (bits=12)

  const int tid  = threadIdx.x;
  const int lane = tid & 63;
  const int wave = tid >> 6;
  const int col  = lane >> 3;   // reader-side column (post-barrier)

  // writer-side column after the fold tree: bit-reversed group index
  const int cw = (((lane >> 3) & 1) << 2) | (((lane >> 4) & 1) << 1) | ((lane >> 5) & 1);
  const int widx = cw * 20 + wave;

  // part2: [col*20 + wave]; stride 20 words keeps the 8 float4-read
  // streams conflict-free.
  __shared__ __align__(16) float part2[160];
  __shared__ __align__(16) float rbuf[8];
  __shared__ float sums[2];
  __shared__ float stot;

  if (tid == 0) { sums[0] = 0.f; sums[1] = 0.f; stot = 0.f; }
  __syncthreads();

  // ---- init: per-row loads and global sums over n, sens_raw ----
  float nv[RPT], sv[RPT];
  float pn = 0.f, ps = 0.f;
  #pragma unroll
  for (int k = 0; k < RPT; ++k) {
    int rr = tid + NT * k;
    nv[k] = fmaf(n_raw[rr], 1e5f, 1e3f);
    sv[k] = sens_raw[rr];
    pn += nv[k];
    ps += sv[k];
  }
  pn = wsum(pn);
  ps = wsum(ps);
  if (lane == 0) { atomicAdd(&sums[0], pn); atomicAdd(&sums[1], ps); }
  __syncthreads();
  const float inv_sumn = __builtin_amdgcn_rcpf(sums[0]);
  const float inv_ss   = __builtin_amdgcn_rcpf(sums[1] + 1e-12f);

  float a_i[RPT], rowc[RPT];
  #pragma unroll
  for (int k = 0; k < RPT; ++k) {
    a_i[k]  = nv[k] * inv_sumn;               // row marginal a_i
    rowc[k] = nv[k] * (sv[k] * inv_ss) * S1C; // S1C * n_i * sens_i
  }

  // ---- b = softmax(phi); each lane keeps b for its reader column ----
  float ph[8];
  #pragma unroll
  for (int j = 0; j < 8; ++j) ph[j] = phi[j];
  float pmx = ph[0];
  #pragma unroll
  for (int j = 1; j < 8; ++j) pmx = fmaxf(pmx, ph[j]);
  float bb[8];
  float bs = 0.f;
  #pragma unroll
  for (int j = 0; j < 8; ++j) { bb[j] = __builtin_amdgcn_exp2f((ph[j] - pmx) * L2E); bs += bb[j]; }
  const float ibs = __builtin_amdgcn_rcpf(bs);
  #pragma unroll
  for (int j = 0; j < 8; ++j) bb[j] *= ibs;
  float b_own;
  {
    float a0 = (col & 1) ? bb[1] : bb[0];
    float a1 = (col & 1) ? bb[3] : bb[2];
    float a2 = (col & 1) ? bb[5] : bb[4];
    float a3 = (col & 1) ? bb[7] : bb[6];
    float c0 = (col & 2) ? a1 : a0;
    float c1 = (col & 2) ? a3 : a2;
    b_own = (col & 4) ? c1 : c0;
  }

  v2f e2[RPT][4];
  v2f R2[4];
  float g2r[8];
  float w0k[RPT];
  #pragma unroll
  for (int j = 0; j < 8; ++j) g2r[j] = 0.f;
  R2[0] = (v2f){1.f, 1.f}; R2[1] = (v2f){1.f, 1.f};
  R2[2] = (v2f){1.f, 1.f}; R2[3] = (v2f){1.f, 1.f};

  #pragma unroll 1
  for (int t = 0; t < NITER; ++t) {
    // ---- refresh: absorb log2(R) into g2, rebuild e from theta (L2-hot) ----
    if ((t & 15) == 0) {
      if (t) {
        g2r[0] += __builtin_amdgcn_logf(R2[0].x);
        g2r[1] += __builtin_amdgcn_logf(R2[0].y);
        g2r[2] += __builtin_amdgcn_logf(R2[1].x);
        g2r[3] += __builtin_amdgcn_logf(R2[1].y);
        g2r[4] += __builtin_amdgcn_logf(R2[2].x);
        g2r[5] += __builtin_amdgcn_logf(R2[2].y);
        g2r[6] += __builtin_amdgcn_logf(R2[3].x);
        g2r[7] += __builtin_amdgcn_logf(R2[3].y);
      }
      #pragma unroll
      for (int k = 0; k < RPT; ++k) {
        const float4* tp = reinterpret_cast<const float4*>(theta + (size_t)(tid + NT * k) * 8);
        float4 t0 = tp[0];
        float4 t1 = tp[1];
        float x0 = fmaf(t0.x, S1C, fmaf(-rowc[k], ERR0, g2r[0]));
        float x1 = fmaf(t0.y, S1C, fmaf(-rowc[k], ERR1, g2r[1]));
        float x2 = fmaf(t0.z, S1C, fmaf(-rowc[k], ERR2, g2r[2]));
        float x3 = fmaf(t0.w, S1C, fmaf(-rowc[k], ERR3, g2r[3]));
        float x4 = fmaf(t1.x, S1C, fmaf(-rowc[k], ERR4, g2r[4]));
        float x5 = fmaf(t1.y, S1C, fmaf(-rowc[k], ERR5, g2r[5]));
        float x6 = fmaf(t1.z, S1C, fmaf(-rowc[k], ERR6, g2r[6]));
        float x7 = fmaf(t1.w, S1C, fmaf(-rowc[k], ERR7, g2r[7]));
        float mx = fmaxf(fmaxf(fmaxf(x0, x1), fmaxf(x2, x3)),
                         fmaxf(fmaxf(x4, x5), fmaxf(x6, x7)));
        e2[k][0] = (v2f){__builtin_amdgcn_exp2f(x0 - mx), __builtin_amdgcn_exp2f(x1 - mx)};
        e2[k][1] = (v2f){__builtin_amdgcn_exp2f(x2 - mx), __builtin_amdgcn_exp2f(x3 - mx)};
        e2[k][2] = (v2f){__builtin_amdgcn_exp2f(x4 - mx), __builtin_amdgcn_exp2f(x5 - mx)};
        e2[k][3] = (v2f){__builtin_amdgcn_exp2f(x6 - mx), __builtin_amdgcn_exp2f(x7 - mx)};
      }
      R2[0] = (v2f){1.f, 1.f}; R2[1] = (v2f){1.f, 1.f};
      R2[2] = (v2f){1.f, 1.f}; R2[3] = (v2f){1.f, 1.f};
    }

    // ---- row phase: S_i = e·R (pk_fma), w0 = a/S, cc += e*w0 (pk_fma) ----
    v2f cca = (v2f){0.f, 0.f}, ccb = (v2f){0.f, 0.f};
    v2f ccc = (v2f){0.f, 0.f}, ccd = (v2f){0.f, 0.f};
    #pragma unroll
    for (int k = 0; k < RPT; ++k) {
      v2f sp = e2[k][0] * R2[0];
      sp = __builtin_elementwise_fma(e2[k][1], R2[1], sp);
      sp = __builtin_elementwise_fma(e2[k][2], R2[2], sp);
      sp = __builtin_elementwise_fma(e2[k][3], R2[3], sp);
      float S  = fmaxf(sp.x + sp.y, 1e-37f);
      float w0 = a_i[k] * __builtin_amdgcn_rcpf(S);
      w0k[k] = w0;
      v2f wv = (v2f){w0, w0};
      cca = __builtin_elementwise_fma(e2[k][0], wv, cca);
      ccb = __builtin_elementwise_fma(e2[k][1], wv, ccb);
      ccc = __builtin_elementwise_fma(e2[k][2], wv, ccc);
      ccd = __builtin_elementwise_fma(e2[k][3], wv, ccd);
    }

    // ---- fold-and-halve reduction over lane bits 3,4,5 ----
    float s0 = dpp_add<0x128>(cca.x);
    float s1 = dpp_add<0x128>(cca.y);
    float s2 = dpp_add<0x128>(ccb.x);
    float s3 = dpp_add<0x128>(ccb.y);
    float s4 = dpp_add<0x128>(ccc.x);
    float s5 = dpp_add<0x128>(ccc.y);
    float s6 = dpp_add<0x128>(ccd.x);
    float s7 = dpp_add<0x128>(ccd.y);
    bool hb3 = (lane & 8) != 0;
    float k0 = hb3 ? s4 : s0;
    float k1 = hb3 ? s5 : s1;
    float k2 = hb3 ? s6 : s2;
    float k3 = hb3 ? s7 : s3;
    k0 += __shfl_xor(k0, 16);
    k1 += __shfl_xor(k1, 16);
    k2 += __shfl_xor(k2, 16);
    k3 += __shfl_xor(k3, 16);
    bool hb4 = (lane & 16) != 0;
    float u0 = hb4 ? k2 : k0;
    float u1 = hb4 ? k3 : k1;
    u0 += __shfl_xor(u0, 32);
    u1 += __shfl_xor(u1, 32);
    float val = ((lane & 32) != 0) ? u1 : u0;
    val = dpp_add<0xB1>(val);    // xor1
    val = dpp_add<0x4E>(val);    // xor2
    val = dpp_add<0x141>(val);   // xor4 (valid after xor1,xor2)

    if ((lane & 7) == 0) part2[widx] = val;
    __syncthreads();

    // ---- wave 0 alone finishes cross-wave sum and publishes R ----
    if (wave == 0) {
      const float4* pp = reinterpret_cast<const float4*>(&part2[col * 20]);
      float4 q0 = pp[0], q1 = pp[1], q2 = pp[2], q3 = pp[3];
      float acc = ((q0.x + q0.y) + (q0.z + q0.w)) + ((q1.x + q1.y) + (q1.z + q1.w))
                + ((q2.x + q2.y) + (q2.z + q2.w)) + ((q3.x + q3.y) + (q3.z + q3.w));
      acc = fmaxf(acc, 1e-35f);
      float rown = fminf(b_own * __builtin_amdgcn_rcpf(acc), CLAMP);
      if ((lane & 7) == 0) rbuf[col] = rown;
    }
    __syncthreads();

    // ---- all lanes fetch R via 2 broadcast b128 reads; early exit ----
    {
      const float4* rp = reinterpret_cast<const float4*>(&rbuf[0]);
      float4 q0 = rp[0], q1 = rp[1];
      R2[0] = (v2f){q0.x, q0.y};
      R2[1] = (v2f){q0.z, q0.w};
      R2[2] = (v2f){q1.x, q1.y};
      R2[3] = (v2f){q1.z, q1.w};
      // fixed point reached -> remaining iterations are numerically idle.
      // R2 is identical across all threads: uniform branch, all waves
      // exit at the same t (barrier-safe).
      float dmax = fmaxf(
        fmaxf(fmaxf(fabsf(q0.x - 1.f), fabsf(q0.y - 1.f)),
              fmaxf(fabsf(q0.z - 1.f), fabsf(q0.w - 1.f))),
        fmaxf(fmaxf(fabsf(q1.x - 1.f), fabsf(q1.y - 1.f)),
              fmaxf(fabsf(q1.z - 1.f), fabsf(q1.w - 1.f))));
      if (t > 24 && dmax < 3e-6f) break;
    }
  }

  // ---- epilogue: P = e * w0 * R, normalize by global total ----
  float lsum = 0.f;
  #pragma unroll
  for (int k = 0; k < RPT; ++k) {
    v2f wv = (v2f){w0k[k], w0k[k]};
    e2[k][0] = e2[k][0] * wv * R2[0];
    e2[k][1] = e2[k][1] * wv * R2[1];
    e2[k][2] = e2[k][2] * wv * R2[2];
    e2[k][3] = e2[k][3] * wv * R2[3];
    lsum += (e2[k][0].x + e2[k][0].y) + (e2[k][1].x + e2[k][1].y)
          + (e2[k][2].x + e2[k][2].y) + (e2[k][3].x + e2[k][3].y);
  }
  lsum = wsum(lsum);
  if (lane == 0) atomicAdd(&stot, lsum);
  __syncthreads();
  const float itot = __builtin_amdgcn_rcpf(stot);
  #pragma unroll
  for (int k = 0; k < RPT; ++k) {
    float4 o0 = make_float4(e2[k][0].x * itot, e2[k][0].y * itot,
                            e2[k][1].x * itot, e2[k][1].y * itot);
    float4 o1 = make_float4(e2[k][2].x * itot, e2[k][2].y * itot,
                            e2[k][3].x * itot, e2[k][3].y * itot);
    float4* op = reinterpret_cast<float4*>(out + (size_t)(tid + NT * k) * 8);
    op[0] = o0;
    op[1] = o1;
  }
}

extern "C" void kernel_launch(void* const* d_in, const int* in_sizes, int n_in,
                              void* d_out, int out_size, void* d_ws, size_t ws_size,
                              hipStream_t stream) {
  const float* theta    = (const float*)d_in[0];
  const float* phi      = (const float*)d_in[1];
  const float* sens_raw = (const float*)d_in[2];
  const float* n_raw    = (const float*)d_in[3];
  float* out = (float*)d_out;
  hipLaunchKernelGGL(sinkhorn_k, dim3(1), dim3(NT), 0, stream,
                     theta, phi, sens_raw, n_raw, out);
}

// Round 9
// 316.771 us; speedup vs baseline: 1.1532x; 1.1532x over previous
//
#include <hip/hip_runtime.h>

#define NT 512
#define RPT 16
#define NITER 200

typedef float v2f __attribute__((ext_vector_type(2)));

// v += dpp-partner(v).  CTRL: 0x128=row_ror:8 (==xor8 in 16-row),
// 0xB1=quad_perm(1,0,3,2)==xor1, 0x4E=quad_perm(2,3,0,1)==xor2,
// 0x141=row_half_mirror (==xor4 once xor1,xor2 are done).
template <int CTRL>
__device__ __forceinline__ float dpp_add(float v) {
  int x = __builtin_amdgcn_update_dpp(0, __float_as_int(v), CTRL, 0xF, 0xF, true);
  return v + __int_as_float(x);
}

__device__ __forceinline__ float wsum(float v) {
  v += __shfl_xor(v, 1);
  v += __shfl_xor(v, 2);
  v += __shfl_xor(v, 4);
  v += __shfl_xor(v, 8);
  v += __shfl_xor(v, 16);
  v += __shfl_xor(v, 32);
  return v;
}

// Sinkhorn, scale-invariant multiplicative form with STATIC e between
// refreshes. Round-7 structure, re-blocked: NT=512 x RPT=16.
// Why: at NT=1024 (4 waves/EU min) the reg budget is 128/wave and the
// allocator split 64 arch + 64 AGPR, parking e2 in AGPRs -> ~128
// v_accvgpr_read per iter (the measured ~2x VALU bloat). 8 waves
// (launch_bounds(512,2)) unlocks the 256-reg budget: e2 (128 floats)
// lives in arch VGPRs, zero accvgpr churn. Early-exit removed (round 8:
// never fired; |R-1| floor > 3e-6 at this EPS).
__global__ void __launch_bounds__(NT, 2)
sinkhorn_k(
    const float* __restrict__ theta,
    const float* __restrict__ phi,
    const float* __restrict__ sens_raw,
    const float* __restrict__ n_raw,
    float* __restrict__ out)
{
  constexpr float S1C = 72.13475204444817f;      // (1/EPS) * log2(e)
  constexpr float L2E = 1.4426950408889634f;
  constexpr float CLAMP = 1.152921504606847e18f; // 2^60
  constexpr float ERR0 = 6.25e-2f;               // 2^-4   (bits=2)
  constexpr float ERR1 = 1.5625e-2f;             // 2^-6   (bits=3)
  constexpr float ERR2 = 3.90625e-3f;            // 2^-8   (bits=4)
  constexpr float ERR3 = 9.765625e-4f;           // 2^-10  (bits=5)
  constexpr float ERR4 = 2.44140625e-4f;         // 2^-12  (bits=6)
  constexpr float ERR5 = 1.52587890625e-5f;      // 2^-16  (bits=8)
  constexpr float ERR6 = 9.5367431640625e-7f;    // 2^-20  (bits=10)
  constexpr float ERR7 = 5.9604644775390625e-8f; // 2^-24  (bits=12)

  const int tid  = threadIdx.x;
  const int lane = tid & 63;
  const int wave = tid >> 6;    // 0..7
  const int col  = lane >> 3;   // reader-side column (post-barrier)

  // writer-side column after the fold tree: bit-reversed group index
  const int cw = (((lane >> 3) & 1) << 2) | (((lane >> 4) & 1) << 1) | ((lane >> 5) & 1);
  const int widx = cw * 20 + wave;

  // part2: [col*20 + wave], wave<8; stride 20 words keeps the 8
  // 2xfloat4-read streams conflict-free (bases 20c mod 32 all distinct).
  __shared__ __align__(16) float part2[160];
  __shared__ __align__(16) float rbuf[8];
  __shared__ float sums[2];
  __shared__ float stot;

  if (tid == 0) { sums[0] = 0.f; sums[1] = 0.f; stot = 0.f; }
  __syncthreads();

  // ---- init: per-row loads and global sums over n, sens_raw ----
  float nv[RPT], sv[RPT];
  float pn = 0.f, ps = 0.f;
  #pragma unroll
  for (int k = 0; k < RPT; ++k) {
    int rr = tid + NT * k;
    nv[k] = fmaf(n_raw[rr], 1e5f, 1e3f);
    sv[k] = sens_raw[rr];
    pn += nv[k];
    ps += sv[k];
  }
  pn = wsum(pn);
  ps = wsum(ps);
  if (lane == 0) { atomicAdd(&sums[0], pn); atomicAdd(&sums[1], ps); }
  __syncthreads();
  const float inv_sumn = __builtin_amdgcn_rcpf(sums[0]);
  const float inv_ss   = __builtin_amdgcn_rcpf(sums[1] + 1e-12f);

  float a_i[RPT], rowc[RPT];
  #pragma unroll
  for (int k = 0; k < RPT; ++k) {
    a_i[k]  = nv[k] * inv_sumn;               // row marginal a_i
    rowc[k] = nv[k] * (sv[k] * inv_ss) * S1C; // S1C * n_i * sens_i
  }

  // ---- b = softmax(phi); each lane keeps b for its reader column ----
  float ph[8];
  #pragma unroll
  for (int j = 0; j < 8; ++j) ph[j] = phi[j];
  float pmx = ph[0];
  #pragma unroll
  for (int j = 1; j < 8; ++j) pmx = fmaxf(pmx, ph[j]);
  float bb[8];
  float bs = 0.f;
  #pragma unroll
  for (int j = 0; j < 8; ++j) { bb[j] = __builtin_amdgcn_exp2f((ph[j] - pmx) * L2E); bs += bb[j]; }
  const float ibs = __builtin_amdgcn_rcpf(bs);
  #pragma unroll
  for (int j = 0; j < 8; ++j) bb[j] *= ibs;
  float b_own;
  {
    float a0 = (col & 1) ? bb[1] : bb[0];
    float a1 = (col & 1) ? bb[3] : bb[2];
    float a2 = (col & 1) ? bb[5] : bb[4];
    float a3 = (col & 1) ? bb[7] : bb[6];
    float c0 = (col & 2) ? a1 : a0;
    float c1 = (col & 2) ? a3 : a2;
    b_own = (col & 4) ? c1 : c0;
  }

  v2f e2[RPT][4];
  v2f R2[4];
  float g2r[8];
  float w0k[RPT];
  #pragma unroll
  for (int j = 0; j < 8; ++j) g2r[j] = 0.f;
  R2[0] = (v2f){1.f, 1.f}; R2[1] = (v2f){1.f, 1.f};
  R2[2] = (v2f){1.f, 1.f}; R2[3] = (v2f){1.f, 1.f};

  #pragma unroll 1
  for (int t = 0; t < NITER; ++t) {
    // ---- refresh: absorb log2(R) into g2, rebuild e from theta (L2-hot) ----
    if ((t & 15) == 0) {
      if (t) {
        g2r[0] += __builtin_amdgcn_logf(R2[0].x);
        g2r[1] += __builtin_amdgcn_logf(R2[0].y);
        g2r[2] += __builtin_amdgcn_logf(R2[1].x);
        g2r[3] += __builtin_amdgcn_logf(R2[1].y);
        g2r[4] += __builtin_amdgcn_logf(R2[2].x);
        g2r[5] += __builtin_amdgcn_logf(R2[2].y);
        g2r[6] += __builtin_amdgcn_logf(R2[3].x);
        g2r[7] += __builtin_amdgcn_logf(R2[3].y);
      }
      #pragma unroll
      for (int k = 0; k < RPT; ++k) {
        const float4* tp = reinterpret_cast<const float4*>(theta + (size_t)(tid + NT * k) * 8);
        float4 t0 = tp[0];
        float4 t1 = tp[1];
        float x0 = fmaf(t0.x, S1C, fmaf(-rowc[k], ERR0, g2r[0]));
        float x1 = fmaf(t0.y, S1C, fmaf(-rowc[k], ERR1, g2r[1]));
        float x2 = fmaf(t0.z, S1C, fmaf(-rowc[k], ERR2, g2r[2]));
        float x3 = fmaf(t0.w, S1C, fmaf(-rowc[k], ERR3, g2r[3]));
        float x4 = fmaf(t1.x, S1C, fmaf(-rowc[k], ERR4, g2r[4]));
        float x5 = fmaf(t1.y, S1C, fmaf(-rowc[k], ERR5, g2r[5]));
        float x6 = fmaf(t1.z, S1C, fmaf(-rowc[k], ERR6, g2r[6]));
        float x7 = fmaf(t1.w, S1C, fmaf(-rowc[k], ERR7, g2r[7]));
        float mx = fmaxf(fmaxf(fmaxf(x0, x1), fmaxf(x2, x3)),
                         fmaxf(fmaxf(x4, x5), fmaxf(x6, x7)));
        e2[k][0] = (v2f){__builtin_amdgcn_exp2f(x0 - mx), __builtin_amdgcn_exp2f(x1 - mx)};
        e2[k][1] = (v2f){__builtin_amdgcn_exp2f(x2 - mx), __builtin_amdgcn_exp2f(x3 - mx)};
        e2[k][2] = (v2f){__builtin_amdgcn_exp2f(x4 - mx), __builtin_amdgcn_exp2f(x5 - mx)};
        e2[k][3] = (v2f){__builtin_amdgcn_exp2f(x6 - mx), __builtin_amdgcn_exp2f(x7 - mx)};
      }
      R2[0] = (v2f){1.f, 1.f}; R2[1] = (v2f){1.f, 1.f};
      R2[2] = (v2f){1.f, 1.f}; R2[3] = (v2f){1.f, 1.f};
    }

    // ---- row phase: S_i = e·R (pk_fma), w0 = a/S, cc += e*w0 (pk_fma) ----
    v2f cca = (v2f){0.f, 0.f}, ccb = (v2f){0.f, 0.f};
    v2f ccc = (v2f){0.f, 0.f}, ccd = (v2f){0.f, 0.f};
    #pragma unroll
    for (int k = 0; k < RPT; ++k) {
      v2f sp = e2[k][0] * R2[0];
      sp = __builtin_elementwise_fma(e2[k][1], R2[1], sp);
      sp = __builtin_elementwise_fma(e2[k][2], R2[2], sp);
      sp = __builtin_elementwise_fma(e2[k][3], R2[3], sp);
      float S  = fmaxf(sp.x + sp.y, 1e-37f);
      float w0 = a_i[k] * __builtin_amdgcn_rcpf(S);
      w0k[k] = w0;
      v2f wv = (v2f){w0, w0};
      cca = __builtin_elementwise_fma(e2[k][0], wv, cca);
      ccb = __builtin_elementwise_fma(e2[k][1], wv, ccb);
      ccc = __builtin_elementwise_fma(e2[k][2], wv, ccc);
      ccd = __builtin_elementwise_fma(e2[k][3], wv, ccd);
    }

    // ---- fold-and-halve reduction over lane bits 3,4,5 ----
    float s0 = dpp_add<0x128>(cca.x);
    float s1 = dpp_add<0x128>(cca.y);
    float s2 = dpp_add<0x128>(ccb.x);
    float s3 = dpp_add<0x128>(ccb.y);
    float s4 = dpp_add<0x128>(ccc.x);
    float s5 = dpp_add<0x128>(ccc.y);
    float s6 = dpp_add<0x128>(ccd.x);
    float s7 = dpp_add<0x128>(ccd.y);
    bool hb3 = (lane & 8) != 0;
    float k0 = hb3 ? s4 : s0;
    float k1 = hb3 ? s5 : s1;
    float k2 = hb3 ? s6 : s2;
    float k3 = hb3 ? s7 : s3;
    k0 += __shfl_xor(k0, 16);
    k1 += __shfl_xor(k1, 16);
    k2 += __shfl_xor(k2, 16);
    k3 += __shfl_xor(k3, 16);
    bool hb4 = (lane & 16) != 0;
    float u0 = hb4 ? k2 : k0;
    float u1 = hb4 ? k3 : k1;
    u0 += __shfl_xor(u0, 32);
    u1 += __shfl_xor(u1, 32);
    float val = ((lane & 32) != 0) ? u1 : u0;
    val = dpp_add<0xB1>(val);    // xor1
    val = dpp_add<0x4E>(val);    // xor2
    val = dpp_add<0x141>(val);   // xor4 (valid after xor1,xor2)

    if ((lane & 7) == 0) part2[widx] = val;
    __syncthreads();

    // ---- wave 0 alone finishes cross-wave sum (8 partials) and publishes R ----
    if (wave == 0) {
      const float4* pp = reinterpret_cast<const float4*>(&part2[col * 20]);
      float4 q0 = pp[0], q1 = pp[1];
      float acc = ((q0.x + q0.y) + (q0.z + q0.w)) + ((q1.x + q1.y) + (q1.z + q1.w));
      acc = fmaxf(acc, 1e-35f);
      float rown = fminf(b_own * __builtin_amdgcn_rcpf(acc), CLAMP);
      if ((lane & 7) == 0) rbuf[col] = rown;
    }
    __syncthreads();

    // ---- all lanes fetch R via 2 broadcast b128 reads ----
    {
      const float4* rp = reinterpret_cast<const float4*>(&rbuf[0]);
      float4 q0 = rp[0], q1 = rp[1];
      R2[0] = (v2f){q0.x, q0.y};
      R2[1] = (v2f){q0.z, q0.w};
      R2[2] = (v2f){q1.x, q1.y};
      R2[3] = (v2f){q1.z, q1.w};
    }
  }

  // ---- epilogue: P = e * w0 * R, normalize by global total ----
  float lsum = 0.f;
  #pragma unroll
  for (int k = 0; k < RPT; ++k) {
    v2f wv = (v2f){w0k[k], w0k[k]};
    e2[k][0] = e2[k][0] * wv * R2[0];
    e2[k][1] = e2[k][1] * wv * R2[1];
    e2[k][2] = e2[k][2] * wv * R2[2];
    e2[k][3] = e2[k][3] * wv * R2[3];
    lsum += (e2[k][0].x + e2[k][0].y) + (e2[k][1].x + e2[k][1].y)
          + (e2[k][2].x + e2[k][2].y) + (e2[k][3].x + e2[k][3].y);
  }
  lsum = wsum(lsum);
  if (lane == 0) atomicAdd(&stot, lsum);
  __syncthreads();
  const float itot = __builtin_amdgcn_rcpf(stot);
  #pragma unroll
  for (int k = 0; k < RPT; ++k) {
    float4 o0 = make_float4(e2[k][0].x * itot, e2[k][0].y * itot,
                            e2[k][1].x * itot, e2[k][1].y * itot);
    float4 o1 = make_float4(e2[k][2].x * itot, e2[k][2].y * itot,
                            e2[k][3].x * itot, e2[k][3].y * itot);
    float4* op = reinterpret_cast<float4*>(out + (size_t)(tid + NT * k) * 8);
    op[0] = o0;
    op[1] = o1;
  }
}

extern "C" void kernel_launch(void* const* d_in, const int* in_sizes, int n_in,
                              void* d_out, int out_size, void* d_ws, size_t ws_size,
                              hipStream_t stream) {
  const float* theta    = (const float*)d_in[0];
  const float* phi      = (const float*)d_in[1];
  const float* sens_raw = (const float*)d_in[2];
  const float* n_raw    = (const float*)d_in[3];
  float* out = (float*)d_out;
  hipLaunchKernelGGL(sinkhorn_k, dim3(1), dim3(NT), 0, stream,
                     theta, phi, sens_raw, n_raw, out);
}

// Round 10
// 315.622 us; speedup vs baseline: 1.1574x; 1.0036x over previous
//
#include <hip/hip_runtime.h>

#define NT 512
#define RPT 16
#define NITER 200

typedef float v2f __attribute__((ext_vector_type(2)));

// v += dpp-partner(v).  CTRL: 0x128=row_ror:8 (==xor8 in 16-row),
// 0xB1=quad_perm(1,0,3,2)==xor1, 0x4E=quad_perm(2,3,0,1)==xor2,
// 0x141=row_half_mirror (==xor4 once xor1,xor2 are done).
template <int CTRL>
__device__ __forceinline__ float dpp_add(float v) {
  int x = __builtin_amdgcn_update_dpp(0, __float_as_int(v), CTRL, 0xF, 0xF, true);
  return v + __int_as_float(x);
}

__device__ __forceinline__ float wsum(float v) {
  v += __shfl_xor(v, 1);
  v += __shfl_xor(v, 2);
  v += __shfl_xor(v, 4);
  v += __shfl_xor(v, 8);
  v += __shfl_xor(v, 16);
  v += __shfl_xor(v, 32);
  return v;
}

// Sinkhorn, scale-invariant multiplicative form with STATIC e between
// refreshes. NT=512 x RPT=16. Round-9 kernel with ONE delta:
// __launch_bounds__(512, 1). Rationale: grid is a single 512-thread block,
// so real occupancy is pinned at 8 waves/CU regardless of the allocator's
// budget. (512,2) capped regs at 256/wave and the allocator split
// 124 arch + ~128 AGPR, leaving e2 in AGPRs (accvgpr churn = the ~900
// cyc/iter VALU gap). (512,1) raises the budget to 512 -> whole working
// set (~200 floats) fits in architectural VGPRs, zero AGPR traffic.
__global__ void __launch_bounds__(NT, 1)
sinkhorn_k(
    const float* __restrict__ theta,
    const float* __restrict__ phi,
    const float* __restrict__ sens_raw,
    const float* __restrict__ n_raw,
    float* __restrict__ out)
{
  constexpr float S1C = 72.13475204444817f;      // (1/EPS) * log2(e)
  constexpr float L2E = 1.4426950408889634f;
  constexpr float CLAMP = 1.152921504606847e18f; // 2^60
  constexpr float ERR0 = 6.25e-2f;               // 2^-4   (bits=2)
  constexpr float ERR1 = 1.5625e-2f;             // 2^-6   (bits=3)
  constexpr float ERR2 = 3.90625e-3f;            // 2^-8   (bits=4)
  constexpr float ERR3 = 9.765625e-4f;           // 2^-10  (bits=5)
  constexpr float ERR4 = 2.44140625e-4f;         // 2^-12  (bits=6)
  constexpr float ERR5 = 1.52587890625e-5f;      // 2^-16  (bits=8)
  constexpr float ERR6 = 9.5367431640625e-7f;    // 2^-20  (bits=10)
  constexpr float ERR7 = 5.9604644775390625e-8f; // 2^-24  (bits=12)

  const int tid  = threadIdx.x;
  const int lane = tid & 63;
  const int wave = tid >> 6;    // 0..7
  const int col  = lane >> 3;   // reader-side column (post-barrier)

  // writer-side column after the fold tree: bit-reversed group index
  const int cw = (((lane >> 3) & 1) << 2) | (((lane >> 4) & 1) << 1) | ((lane >> 5) & 1);
  const int widx = cw * 20 + wave;

  // part2: [col*20 + wave], wave<8; stride 20 words keeps the 8
  // 2xfloat4-read streams conflict-free (bases 20c mod 32 all distinct).
  __shared__ __align__(16) float part2[160];
  __shared__ __align__(16) float rbuf[8];
  __shared__ float sums[2];
  __shared__ float stot;

  if (tid == 0) { sums[0] = 0.f; sums[1] = 0.f; stot = 0.f; }
  __syncthreads();

  // ---- init: per-row loads and global sums over n, sens_raw ----
  float nv[RPT], sv[RPT];
  float pn = 0.f, ps = 0.f;
  #pragma unroll
  for (int k = 0; k < RPT; ++k) {
    int rr = tid + NT * k;
    nv[k] = fmaf(n_raw[rr], 1e5f, 1e3f);
    sv[k] = sens_raw[rr];
    pn += nv[k];
    ps += sv[k];
  }
  pn = wsum(pn);
  ps = wsum(ps);
  if (lane == 0) { atomicAdd(&sums[0], pn); atomicAdd(&sums[1], ps); }
  __syncthreads();
  const float inv_sumn = __builtin_amdgcn_rcpf(sums[0]);
  const float inv_ss   = __builtin_amdgcn_rcpf(sums[1] + 1e-12f);

  float a_i[RPT], rowc[RPT];
  #pragma unroll
  for (int k = 0; k < RPT; ++k) {
    a_i[k]  = nv[k] * inv_sumn;               // row marginal a_i
    rowc[k] = nv[k] * (sv[k] * inv_ss) * S1C; // S1C * n_i * sens_i
  }

  // ---- b = softmax(phi); each lane keeps b for its reader column ----
  float ph[8];
  #pragma unroll
  for (int j = 0; j < 8; ++j) ph[j] = phi[j];
  float pmx = ph[0];
  #pragma unroll
  for (int j = 1; j < 8; ++j) pmx = fmaxf(pmx, ph[j]);
  float bb[8];
  float bs = 0.f;
  #pragma unroll
  for (int j = 0; j < 8; ++j) { bb[j] = __builtin_amdgcn_exp2f((ph[j] - pmx) * L2E); bs += bb[j]; }
  const float ibs = __builtin_amdgcn_rcpf(bs);
  #pragma unroll
  for (int j = 0; j < 8; ++j) bb[j] *= ibs;
  float b_own;
  {
    float a0 = (col & 1) ? bb[1] : bb[0];
    float a1 = (col & 1) ? bb[3] : bb[2];
    float a2 = (col & 1) ? bb[5] : bb[4];
    float a3 = (col & 1) ? bb[7] : bb[6];
    float c0 = (col & 2) ? a1 : a0;
    float c1 = (col & 2) ? a3 : a2;
    b_own = (col & 4) ? c1 : c0;
  }

  v2f e2[RPT][4];
  v2f R2[4];
  float g2r[8];
  float w0k[RPT];
  #pragma unroll
  for (int j = 0; j < 8; ++j) g2r[j] = 0.f;
  R2[0] = (v2f){1.f, 1.f}; R2[1] = (v2f){1.f, 1.f};
  R2[2] = (v2f){1.f, 1.f}; R2[3] = (v2f){1.f, 1.f};

  #pragma unroll 1
  for (int t = 0; t < NITER; ++t) {
    // ---- refresh: absorb log2(R) into g2, rebuild e from theta (L2-hot) ----
    if ((t & 15) == 0) {
      if (t) {
        g2r[0] += __builtin_amdgcn_logf(R2[0].x);
        g2r[1] += __builtin_amdgcn_logf(R2[0].y);
        g2r[2] += __builtin_amdgcn_logf(R2[1].x);
        g2r[3] += __builtin_amdgcn_logf(R2[1].y);
        g2r[4] += __builtin_amdgcn_logf(R2[2].x);
        g2r[5] += __builtin_amdgcn_logf(R2[2].y);
        g2r[6] += __builtin_amdgcn_logf(R2[3].x);
        g2r[7] += __builtin_amdgcn_logf(R2[3].y);
      }
      #pragma unroll
      for (int k = 0; k < RPT; ++k) {
        const float4* tp = reinterpret_cast<const float4*>(theta + (size_t)(tid + NT * k) * 8);
        float4 t0 = tp[0];
        float4 t1 = tp[1];
        float x0 = fmaf(t0.x, S1C, fmaf(-rowc[k], ERR0, g2r[0]));
        float x1 = fmaf(t0.y, S1C, fmaf(-rowc[k], ERR1, g2r[1]));
        float x2 = fmaf(t0.z, S1C, fmaf(-rowc[k], ERR2, g2r[2]));
        float x3 = fmaf(t0.w, S1C, fmaf(-rowc[k], ERR3, g2r[3]));
        float x4 = fmaf(t1.x, S1C, fmaf(-rowc[k], ERR4, g2r[4]));
        float x5 = fmaf(t1.y, S1C, fmaf(-rowc[k], ERR5, g2r[5]));
        float x6 = fmaf(t1.z, S1C, fmaf(-rowc[k], ERR6, g2r[6]));
        float x7 = fmaf(t1.w, S1C, fmaf(-rowc[k], ERR7, g2r[7]));
        float mx = fmaxf(fmaxf(fmaxf(x0, x1), fmaxf(x2, x3)),
                         fmaxf(fmaxf(x4, x5), fmaxf(x6, x7)));
        e2[k][0] = (v2f){__builtin_amdgcn_exp2f(x0 - mx), __builtin_amdgcn_exp2f(x1 - mx)};
        e2[k][1] = (v2f){__builtin_amdgcn_exp2f(x2 - mx), __builtin_amdgcn_exp2f(x3 - mx)};
        e2[k][2] = (v2f){__builtin_amdgcn_exp2f(x4 - mx), __builtin_amdgcn_exp2f(x5 - mx)};
        e2[k][3] = (v2f){__builtin_amdgcn_exp2f(x6 - mx), __builtin_amdgcn_exp2f(x7 - mx)};
      }
      R2[0] = (v2f){1.f, 1.f}; R2[1] = (v2f){1.f, 1.f};
      R2[2] = (v2f){1.f, 1.f}; R2[3] = (v2f){1.f, 1.f};
    }

    // ---- row phase: S_i = e·R (pk_fma), w0 = a/S, cc += e*w0 (pk_fma) ----
    v2f cca = (v2f){0.f, 0.f}, ccb = (v2f){0.f, 0.f};
    v2f ccc = (v2f){0.f, 0.f}, ccd = (v2f){0.f, 0.f};
    #pragma unroll
    for (int k = 0; k < RPT; ++k) {
      v2f sp = e2[k][0] * R2[0];
      sp = __builtin_elementwise_fma(e2[k][1], R2[1], sp);
      sp = __builtin_elementwise_fma(e2[k][2], R2[2], sp);
      sp = __builtin_elementwise_fma(e2[k][3], R2[3], sp);
      float S  = fmaxf(sp.x + sp.y, 1e-37f);
      float w0 = a_i[k] * __builtin_amdgcn_rcpf(S);
      w0k[k] = w0;
      v2f wv = (v2f){w0, w0};
      cca = __builtin_elementwise_fma(e2[k][0], wv, cca);
      ccb = __builtin_elementwise_fma(e2[k][1], wv, ccb);
      ccc = __builtin_elementwise_fma(e2[k][2], wv, ccc);
      ccd = __builtin_elementwise_fma(e2[k][3], wv, ccd);
    }

    // ---- fold-and-halve reduction over lane bits 3,4,5 ----
    float s0 = dpp_add<0x128>(cca.x);
    float s1 = dpp_add<0x128>(cca.y);
    float s2 = dpp_add<0x128>(ccb.x);
    float s3 = dpp_add<0x128>(ccb.y);
    float s4 = dpp_add<0x128>(ccc.x);
    float s5 = dpp_add<0x128>(ccc.y);
    float s6 = dpp_add<0x128>(ccd.x);
    float s7 = dpp_add<0x128>(ccd.y);
    bool hb3 = (lane & 8) != 0;
    float k0 = hb3 ? s4 : s0;
    float k1 = hb3 ? s5 : s1;
    float k2 = hb3 ? s6 : s2;
    float k3 = hb3 ? s7 : s3;
    k0 += __shfl_xor(k0, 16);
    k1 += __shfl_xor(k1, 16);
    k2 += __shfl_xor(k2, 16);
    k3 += __shfl_xor(k3, 16);
    bool hb4 = (lane & 16) != 0;
    float u0 = hb4 ? k2 : k0;
    float u1 = hb4 ? k3 : k1;
    u0 += __shfl_xor(u0, 32);
    u1 += __shfl_xor(u1, 32);
    float val = ((lane & 32) != 0) ? u1 : u0;
    val = dpp_add<0xB1>(val);    // xor1
    val = dpp_add<0x4E>(val);    // xor2
    val = dpp_add<0x141>(val);   // xor4 (valid after xor1,xor2)

    if ((lane & 7) == 0) part2[widx] = val;
    __syncthreads();

    // ---- wave 0 alone finishes cross-wave sum (8 partials) and publishes R ----
    if (wave == 0) {
      const float4* pp = reinterpret_cast<const float4*>(&part2[col * 20]);
      float4 q0 = pp[0], q1 = pp[1];
      float acc = ((q0.x + q0.y) + (q0.z + q0.w)) + ((q1.x + q1.y) + (q1.z + q1.w));
      acc = fmaxf(acc, 1e-35f);
      float rown = fminf(b_own * __builtin_amdgcn_rcpf(acc), CLAMP);
      if ((lane & 7) == 0) rbuf[col] = rown;
    }
    __syncthreads();

    // ---- all lanes fetch R via 2 broadcast b128 reads ----
    {
      const float4* rp = reinterpret_cast<const float4*>(&rbuf[0]);
      float4 q0 = rp[0], q1 = rp[1];
      R2[0] = (v2f){q0.x, q0.y};
      R2[1] = (v2f){q0.z, q0.w};
      R2[2] = (v2f){q1.x, q1.y};
      R2[3] = (v2f){q1.z, q1.w};
    }
  }

  // ---- epilogue: P = e * w0 * R, normalize by global total ----
  float lsum = 0.f;
  #pragma unroll
  for (int k = 0; k < RPT; ++k) {
    v2f wv = (v2f){w0k[k], w0k[k]};
    e2[k][0] = e2[k][0] * wv * R2[0];
    e2[k][1] = e2[k][1] * wv * R2[1];
    e2[k][2] = e2[k][2] * wv * R2[2];
    e2[k][3] = e2[k][3] * wv * R2[3];
    lsum += (e2[k][0].x + e2[k][0].y) + (e2[k][1].x + e2[k][1].y)
          + (e2[k][2].x + e2[k][2].y) + (e2[k][3].x + e2[k][3].y);
  }
  lsum = wsum(lsum);
  if (lane == 0) atomicAdd(&stot, lsum);
  __syncthreads();
  const float itot = __builtin_amdgcn_rcpf(stot);
  #pragma unroll
  for (int k = 0; k < RPT; ++k) {
    float4 o0 = make_float4(e2[k][0].x * itot, e2[k][0].y * itot,
                            e2[k][1].x * itot, e2[k][1].y * itot);
    float4 o1 = make_float4(e2[k][2].x * itot, e2[k][2].y * itot,
                            e2[k][3].x * itot, e2[k][3].y * itot);
    float4* op = reinterpret_cast<float4*>(out + (size_t)(tid + NT * k) * 8);
    op[0] = o0;
    op[1] = o1;
  }
}

extern "C" void kernel_launch(void* const* d_in, const int* in_sizes, int n_in,
                              void* d_out, int out_size, void* d_ws, size_t ws_size,
                              hipStream_t stream) {
  const float* theta    = (const float*)d_in[0];
  const float* phi      = (const float*)d_in[1];
  const float* sens_raw = (const float*)d_in[2];
  const float* n_raw    = (const float*)d_in[3];
  float* out = (float*)d_out;
  hipLaunchKernelGGL(sinkhorn_k, dim3(1), dim3(NT), 0, stream,
                     theta, phi, sens_raw, n_raw, out);
}